// Round 2
// baseline (46293.433 us; speedup 1.0000x reference)
//
#include <hip/hip_runtime.h>
#include <hip/hip_fp16.h>

// ============================================================================
// 2-layer LSTM with projection (proj_size=128, H=1024, B=64, T=2048)
//
// Design (round 2 = round 1 + wall-clock hang-proofing; round 1 never ran —
// container died before push, infra flake):
//  - 64 workgroups x 256 threads: blocks 0..31 = layer 0, 32..63 = layer 1
//    (layers pipelined; layer1 consumes layer0's h1 through a 64-deep ring).
//  - Each WG owns an H-slice of 32 (=> 128 gate rows: i,f,g,o interleaved by
//    16-col MFMA tiles), all 64 batches. Gate GEMM [64,256]x[256,128] via
//    v_mfma_f32_16x16x32_f16; weights live in REGISTERS (preloaded once,
//    zero weight traffic per step -- per-CU L2 BW is the killer otherwise).
//  - Per step: phase1 (gates -> elementwise -> s -> partial projection
//    [64,32]x[32,128] -> global partial) ... flag ... phase2 (each WG reduces
//    a 4-wide h-column slice over the 32 partials, writes h in MFMA-fragment
//    layout) ... flag.  Flags = monotonic agent-scope atomics, data fenced
//    with __threadfence (wbl2/inv on gfx950).  Buffers double-buffered;
//    overwrite safety follows from flag ordering (see comments).
//  - f16 MFMA inputs (2^-11 quant -- bf16 would blow the 4.9e-4 abs threshold),
//    fp32 accumulators, fp32 c-state in registers.
//  - HANG-PROOF: all spin loops carry a collective wall-clock timeout
//    (s_memrealtime, ~2 s from kernel start). On timeout the WG abandons the
//    whole t-loop; the global deadline makes every other WG follow within one
//    wait. Worst case = ~2 s run + absmax failure, never a dead container.
//
// Workspace requirement: ~14.3 MB (checked; returns early if insufficient).
// ============================================================================

typedef _Float16 f16;
typedef _Float16 f16x8 __attribute__((ext_vector_type(8)));
typedef float f32x4 __attribute__((ext_vector_type(4)));

#define TSTEPS 2048
#define NW 32
#define RING_N 64
#define TIMEOUT_TICKS 200000000ull   // ~2 s at 100 MHz s_memrealtime

// ---- workspace layout (bytes) ----
#define BSW_OFF   0ull
#define BSW_SZ    (64ull*32768ull*2ull)        // gate-weight frags, 4 MiB
#define WHR_OFF   (BSW_OFF + BSW_SZ)
#define WHR_SZ    (64ull*4096ull*2ull)         // proj-weight frags, 512 KiB
#define BIAS_OFF  (WHR_OFF + WHR_SZ)
#define BIAS_SZ   (8192ull*4ull)               // bih+bhh, both layers
#define HBUF_OFF  (BIAS_OFF + BIAS_SZ)
#define HBUF_SZ   (32768ull*2ull)              // h frag buf: 2 layers x 2 parity x 8192 f16
#define RINGB_OFF (HBUF_OFF + HBUF_SZ)
#define RINGB_SZ  ((unsigned long long)RING_N*8192ull*2ull)  // h1 ring, 1 MiB
#define PART_OFF  (RINGB_OFF + RINGB_SZ)
#define PART_SZ   (2ull*2ull*32ull*8192ull*4ull)             // partial h, 8 MiB
#define FLAG_OFF  (PART_OFF + PART_SZ)
#define FLAG_SZ   (512ull)
#define WS_NEED   (FLAG_OFF + FLAG_SZ)

__device__ __forceinline__ float sigm(float v) {
  float e = __builtin_amdgcn_exp2f(-1.4426950408889634f * v);
  return __builtin_amdgcn_rcpf(1.0f + e);
}
__device__ __forceinline__ float tanh_(float v) {
  float a = fabsf(v);
  float e = __builtin_amdgcn_exp2f(-2.8853900817779268f * a);
  float r = (1.0f - e) * __builtin_amdgcn_rcpf(1.0f + e);
  return copysignf(r, v);
}

// ---------------------------------------------------------------------------
// Setup: pack weights into per-WG MFMA-fragment order (f16), sum biases,
// zero h buffers + flags.  Runs every launch (deterministic).
// Fragment conventions (16x16x32):
//   A-frag: lane l holds A[m = l&15][k = (l>>4)*8 + i], i=0..7  (16B chunk)
//   B-frag: lane l holds B[k = (l>>4)*8 + i][n = l&15]
//   D:      lane l, reg r -> D[m = (l>>4)*4 + r][n = l&15]      (m89-verified)
// ---------------------------------------------------------------------------
__global__ void lstm_setup(
    const float* __restrict__ Wih0, const float* __restrict__ Whh0,
    const float* __restrict__ bih0, const float* __restrict__ bhh0,
    const float* __restrict__ Whr0,
    const float* __restrict__ Wih1, const float* __restrict__ Whh1,
    const float* __restrict__ bih1, const float* __restrict__ bhh1,
    const float* __restrict__ Whr1,
    f16* __restrict__ Bsw, f16* __restrict__ Whrsw, float* __restrict__ bias,
    f16* __restrict__ hbuf, unsigned* __restrict__ flags)
{
  const int blk = blockIdx.x, tid = threadIdx.x;
  if (blk < 64) {
    // gate weights: slice rows = [i|f|g|o] x 32 H-rows of this WG.
    // Bsw[blk][ks][ntG][lane][i] = W'[row_local = ntG*16+(l&15)][k = ks*32+(l>>4)*8+i]
    // W'[row][k] = Whh[grow][k] (k<128) else Wih[grow][k-128]
    const int lyr = blk >> 5, w = blk & 31;
    const float* Whh = lyr ? Whh1 : Whh0;
    const float* Wih = lyr ? Wih1 : Wih0;
    f16* dst = Bsw + (size_t)blk * 32768;
    for (int e = tid; e < 32768; e += 256) {
      int i = e & 7, l = (e >> 3) & 63, ntG = (e >> 9) & 7, ks = e >> 12;
      int k  = ks * 32 + (l >> 4) * 8 + i;
      int rl = ntG * 16 + (l & 15);                    // 0..127
      int grow = (rl >> 5) * 1024 + w * 32 + (rl & 31); // global gate row
      float v = (k < 128) ? Whh[grow * 128 + k] : Wih[grow * 128 + (k - 128)];
      dst[e] = (f16)v;
    }
  } else if (blk < 128) {
    // projection weights (B-frag for [64,32]x[32,128], K=32 in one MFMA):
    // Whrsw[q][pnG][lane][i] = Whr[p = pnG*16+(l&15)][hg = w*32+(l>>4)*8+i]
    const int q = blk - 64, lyr = q >> 5, w = q & 31;
    const float* Whr = lyr ? Whr1 : Whr0;
    f16* dst = Whrsw + (size_t)q * 4096;
    for (int e = tid; e < 4096; e += 256) {
      int i = e & 7, l = (e >> 3) & 63, pnG = e >> 9;
      int p = pnG * 16 + (l & 15);
      int hg = w * 32 + (l >> 4) * 8 + i;
      dst[e] = (f16)Whr[p * 1024 + hg];
    }
  } else if (blk == 128) {
    for (int e = tid; e < 8192; e += 256) {
      int lyr = e >> 12, j = e & 4095;
      bias[e] = lyr ? (bih1[j] + bhh1[j]) : (bih0[j] + bhh0[j]);
    }
  } else {
    for (int e = tid; e < 32768; e += 256) hbuf[e] = (f16)0.f;
    for (int e = tid; e < 128;   e += 256) flags[e] = 0u;
  }
}

// ---------------------------------------------------------------------------
// Main persistent kernel: 64 WGs x 256 thr (4 waves in a 2x2 (wy,wx) grid).
// wave (wy,wx): gate M-tiles {wy*2,wy*2+1}, gate N-tiles {wx,wx+2,wx+4,wx+6}
// (strided so each wave owns all 4 gate types for one 16-wide h''-half ->
//  the elementwise update is fully register-local).
// ---------------------------------------------------------------------------
__global__ __launch_bounds__(256, 1) void lstm_main(
    const float* __restrict__ x, float* __restrict__ out,
    const f16* __restrict__ Bsw, const f16* __restrict__ Whrsw,
    const float* __restrict__ bias, f16* __restrict__ hbuf,
    f16* __restrict__ ring, float* __restrict__ part,
    unsigned* __restrict__ flag1, unsigned* __restrict__ flag2)
{
  const int tid = threadIdx.x;
  const int lane = tid & 63, wv = tid >> 6;
  const int wy = wv >> 1, wx = wv & 1;
  const int l15 = lane & 15, lg = lane >> 4;
  const int w = blockIdx.x & 31, lyr = blockIdx.x >> 5;
  const int pid = tid & 31;

  const unsigned long long tstart = __builtin_amdgcn_s_memrealtime();

  __shared__ f16   s_lds[64][40];     // s values, row=batch (80B stride, 16B-aligned)
  __shared__ float part_lds[128][65]; // partial-h transpose staging (pad 65)

  // ---- preload this WG's weight slice into registers (once) ----
  f16x8 bf[8][4];  // [ks][ntl], ntG = ntl*2+wx
  {
    const f16* bsl = Bsw + (size_t)(lyr * NW + w) * 32768;
#pragma unroll
    for (int ks = 0; ks < 8; ++ks)
#pragma unroll
      for (int ntl = 0; ntl < 4; ++ntl)
        bf[ks][ntl] = *(const f16x8*)(bsl + (((ks * 8 + (ntl * 2 + wx)) * 64 + lane) * 8));
  }
  f16x8 wf[4];     // proj B-frags, pnG = pnl*2+wx
  {
    const f16* wsl = Whrsw + (size_t)(lyr * NW + w) * 4096;
#pragma unroll
    for (int pnl = 0; pnl < 4; ++pnl)
      wf[pnl] = *(const f16x8*)(wsl + (((pnl * 2 + wx) * 64 + lane) * 8));
  }
  float bias_r[4];
#pragma unroll
  for (int ntl = 0; ntl < 4; ++ntl)
    bias_r[ntl] = bias[lyr * 4096 + ntl * 1024 + w * 32 + wx * 16 + l15];

  float c[2][4] = {{0.f,0.f,0.f,0.f},{0.f,0.f,0.f,0.f}};  // c-state per lane

  unsigned* f1L = flag1 + lyr * 32;  // this layer's phase-1 flags
  unsigned* f2L = flag2 + lyr * 32;  // this layer's phase-2 flags
  unsigned* f2_0 = flag2;            // layer0 phase-2 (h1 ready)
  unsigned* f1_1 = flag1 + 32;       // layer1 phase-1 (ring-slot consumed)
  f16* hb = hbuf + lyr * 2 * 8192;

  for (int t = 0; t < TSTEPS; ++t) {
    // ================= phase 1: wait for h_{t-1} (+ h1_t for layer1) =========
    {
      int giveup = 0;
      for (;;) {
        bool ok = __hip_atomic_load(f2L + pid, __ATOMIC_RELAXED, __HIP_MEMORY_SCOPE_AGENT) >= (unsigned)t;
        if (lyr == 1)
          ok &= __hip_atomic_load(f2_0 + pid, __ATOMIC_RELAXED, __HIP_MEMORY_SCOPE_AGENT) >= (unsigned)(t + 1);
        bool to = (__builtin_amdgcn_s_memrealtime() - tstart) > TIMEOUT_TICKS;
        if (__syncthreads_or(to)) { giveup = 1; break; }
        if (__syncthreads_and(ok)) break;
        __builtin_amdgcn_s_sleep(2);
      }
      if (giveup) break;  // collective (syncthreads_or) -> uniform exit
      __threadfence();    // acquire: invalidate caches before cross-WG reads
    }

    // ---- A fragments: [h_{t-1} | x_t]  (h already stored in frag layout) ----
    f16x8 af[2][8];
    {
      const f16* hsrc = hb + ((t + 1) & 1) * 8192;  // parity (t-1)&1
#pragma unroll
      for (int mtl = 0; mtl < 2; ++mtl) {
        const int mtG = wy * 2 + mtl;
#pragma unroll
        for (int ks = 0; ks < 4; ++ks)
          af[mtl][ks] = *(const f16x8*)(hsrc + ((ks * 4 + mtG) * 64 + lane) * 8);
        if (lyr == 0) {
          const int bb = mtG * 16 + l15;
          const float* xp = x + ((size_t)bb * TSTEPS + t) * 128 + lg * 8;
#pragma unroll
          for (int ks2 = 0; ks2 < 4; ++ks2) {
            float4 v0 = *(const float4*)(xp + ks2 * 32);
            float4 v1 = *(const float4*)(xp + ks2 * 32 + 4);
            f16x8 hx;
            hx[0]=(f16)v0.x; hx[1]=(f16)v0.y; hx[2]=(f16)v0.z; hx[3]=(f16)v0.w;
            hx[4]=(f16)v1.x; hx[5]=(f16)v1.y; hx[6]=(f16)v1.z; hx[7]=(f16)v1.w;
            af[mtl][4 + ks2] = hx;
          }
        } else {
          const f16* rsrc = ring + (size_t)(t & (RING_N - 1)) * 8192;
#pragma unroll
          for (int ks2 = 0; ks2 < 4; ++ks2)
            af[mtl][4 + ks2] = *(const f16x8*)(rsrc + ((ks2 * 4 + mtG) * 64 + lane) * 8);
        }
      }
    }

    // ---- gate GEMM: acc[mtl][ntl] = bias + A*B ----
    f32x4 acc[2][4];
#pragma unroll
    for (int mtl = 0; mtl < 2; ++mtl)
#pragma unroll
      for (int ntl = 0; ntl < 4; ++ntl) {
        f32x4 b4 = {bias_r[ntl], bias_r[ntl], bias_r[ntl], bias_r[ntl]};
        acc[mtl][ntl] = b4;
      }
#pragma unroll
    for (int ks = 0; ks < 8; ++ks)
#pragma unroll
      for (int mtl = 0; mtl < 2; ++mtl)
#pragma unroll
        for (int ntl = 0; ntl < 4; ++ntl)
          acc[mtl][ntl] = __builtin_amdgcn_mfma_f32_16x16x32_f16(
              af[mtl][ks], bf[ks][ntl], acc[mtl][ntl], 0, 0, 0);

    // ---- elementwise: ntl IS the gate type (i,f,g,o) for unit (h'',b) ----
#pragma unroll
    for (int mtl = 0; mtl < 2; ++mtl)
#pragma unroll
      for (int r = 0; r < 4; ++r) {
        float gi = acc[mtl][0][r];
        float gf = acc[mtl][1][r];
        float gg = acc[mtl][2][r];
        float go = acc[mtl][3][r];
        float cc = sigm(gf) * c[mtl][r] + sigm(gi) * tanh_(gg);
        c[mtl][r] = cc;
        float s = sigm(go) * tanh_(cc);
        int bb = (wy * 2 + mtl) * 16 + lg * 4 + r;
        s_lds[bb][wx * 16 + l15] = (f16)s;
      }
    __syncthreads();

    // ---- partial projection: [64,32]x[32,128] in one K=32 MFMA per tile ----
    f16x8 ap[2];
#pragma unroll
    for (int pml = 0; pml < 2; ++pml)
      ap[pml] = *(const f16x8*)(&s_lds[(wy * 2 + pml) * 16 + l15][lg * 8]);
    f32x4 pacc[2][4];
#pragma unroll
    for (int pml = 0; pml < 2; ++pml)
#pragma unroll
      for (int pnl = 0; pnl < 4; ++pnl) {
        f32x4 z = {0.f, 0.f, 0.f, 0.f};
        pacc[pml][pnl] = __builtin_amdgcn_mfma_f32_16x16x32_f16(ap[pml], wf[pnl], z, 0, 0, 0);
      }
    // transpose to p-major via LDS, then coalesced store
#pragma unroll
    for (int pml = 0; pml < 2; ++pml)
#pragma unroll
      for (int pnl = 0; pnl < 4; ++pnl)
#pragma unroll
        for (int r = 0; r < 4; ++r)
          part_lds[(pnl * 2 + wx) * 16 + l15][(wy * 2 + pml) * 16 + lg * 4 + r] =
              pacc[pml][pnl][r];
    __syncthreads();
    {
      float* pdst = part + (size_t)((lyr * 2 + (t & 1)) * 32 + w) * 8192;
#pragma unroll 8
      for (int q = 0; q < 32; ++q) {
        int g = tid + q * 256;
        pdst[g] = part_lds[g >> 6][g & 63];
      }
    }
    __syncthreads();  // drains all waves' vmem stores (vmcnt(0)) before release
    if (tid == 0)
      __hip_atomic_store(f1L + w, (unsigned)(t + 1), __ATOMIC_RELEASE, __HIP_MEMORY_SCOPE_AGENT);

    // ================= phase 2: reduce partials for h-column slice ==========
    {
      int giveup = 0;
      for (;;) {
        bool ok = __hip_atomic_load(f1L + pid, __ATOMIC_RELAXED, __HIP_MEMORY_SCOPE_AGENT) >= (unsigned)(t + 1);
        // ring-overwrite throttle: layer0 may lead layer1 by at most RING_N-1 steps
        if (lyr == 0 && t >= RING_N)
          ok &= __hip_atomic_load(f1_1 + pid, __ATOMIC_RELAXED, __HIP_MEMORY_SCOPE_AGENT) >= (unsigned)(t - (RING_N - 1));
        bool to = (__builtin_amdgcn_s_memrealtime() - tstart) > TIMEOUT_TICKS;
        if (__syncthreads_or(to)) { giveup = 1; break; }
        if (__syncthreads_and(ok)) break;
        __builtin_amdgcn_s_sleep(2);
      }
      if (giveup) break;
      __threadfence();
    }
    {
      const int p = w * 4 + wv;   // this thread's h column
      const int bb = lane;        // batch
      const float* psrc = part + (size_t)((lyr * 2 + (t & 1)) * 32) * 8192 + p * 64 + bb;
      float sum = 0.f;
#pragma unroll 8
      for (int j = 0; j < 32; ++j) sum += psrc[(size_t)j * 8192];
      // write h in A-fragment layout (so next step's loads are 16B coalesced)
      const int cidx = (((p >> 5) * 4 + (bb >> 4)) * 64 + ((p >> 3) & 3) * 16 + (bb & 15)) * 8 + (p & 7);
      f16 hv = (f16)sum;
      hb[(t & 1) * 8192 + cidx] = hv;
      if (lyr == 0)
        ring[(size_t)(t & (RING_N - 1)) * 8192 + cidx] = hv;
      else if (t >= TSTEPS - 64)
        out[(size_t)bb * 8192 + (t - (TSTEPS - 64)) * 128 + p] = sum;
    }
    __syncthreads();
    if (tid == 0)
      __hip_atomic_store(f2L + w, (unsigned)(t + 1), __ATOMIC_RELEASE, __HIP_MEMORY_SCOPE_AGENT);
  }
}

extern "C" void kernel_launch(void* const* d_in, const int* in_sizes, int n_in,
                              void* d_out, int out_size, void* d_ws, size_t ws_size,
                              hipStream_t stream)
{
  const float* x    = (const float*)d_in[0];
  const float* Wih0 = (const float*)d_in[1];
  const float* Whh0 = (const float*)d_in[2];
  const float* bih0 = (const float*)d_in[3];
  const float* bhh0 = (const float*)d_in[4];
  const float* Whr0 = (const float*)d_in[5];
  const float* Wih1 = (const float*)d_in[6];
  const float* Whh1 = (const float*)d_in[7];
  const float* bih1 = (const float*)d_in[8];
  const float* bhh1 = (const float*)d_in[9];
  const float* Whr1 = (const float*)d_in[10];

  if (ws_size < WS_NEED) return;  // need ~14.3 MB scratch

  char* ws = (char*)d_ws;
  f16*      Bsw   = (f16*)(ws + BSW_OFF);
  f16*      Whrsw = (f16*)(ws + WHR_OFF);
  float*    bias  = (float*)(ws + BIAS_OFF);
  f16*      hbuf  = (f16*)(ws + HBUF_OFF);
  f16*      ring  = (f16*)(ws + RINGB_OFF);
  float*    part  = (float*)(ws + PART_OFF);
  unsigned* flags = (unsigned*)(ws + FLAG_OFF);
  unsigned* flag1 = flags;        // [2][32]
  unsigned* flag2 = flags + 64;   // [2][32]

  lstm_setup<<<130, 256, 0, stream>>>(Wih0, Whh0, bih0, bhh0, Whr0,
                                      Wih1, Whh1, bih1, bhh1, Whr1,
                                      Bsw, Whrsw, bias, hbuf, flags);
  lstm_main<<<64, 256, 0, stream>>>(x, (float*)d_out, Bsw, Whrsw, bias,
                                    hbuf, ring, part, flag1, flag2);
}

// Round 5
// 22878.117 us; speedup vs baseline: 2.0235x; 2.0235x over previous
//
#include <hip/hip_runtime.h>
#include <hip/hip_fp16.h>

// ============================================================================
// 2-layer LSTM with projection (proj_size=128, H=1024, B=64, T=2048)
//
// Round 5: zero-inline-asm data path. Rounds 3/4 rebuilt cross-WG data flow
// on hand-written sc0sc1 asm and produced two different silent corruptions
// (spilled in-flight outputs; NaN garbage). This round removes the entire
// risk class: EVERY cross-WG access (partials, h frags, ring, flags) is a
// compiler-generated RELAXED AGENT-SCOPE atomic (__hip_atomic_*), which on
// gfx950 lowers to global_load/store ... sc1: L2-bypassing, MALL-coherent,
// NO buffer_wbl2/buffer_inv anywhere (round 2's 46 ms was the fence storm).
//  - Release: s_waitcnt vmcnt(0) (operand-free asm) + __syncthreads (drains
//    all waves) -> relaxed flag store by tid 0.
//  - Acquire: poll loop exit depends on the loaded flag (in-order issue means
//    no post-loop load can issue early) + compiler barrier. sc1 loads read
//    the coherence point, so nothing stale is possible.
//  - Atomics are <=8B: 16B fragments move as u64 pairs (latency path; fine).
//  - Protocol/numerics identical to PASSING round 2 (absmax 1.2e-4):
//    register-resident f16 weights, MFMA gates [64,256]x[256,128] per WG,
//    fp32 c-state, 2-phase flag pipeline, 64-deep ring, part[p][j][b] layout
//    with butterfly reduce (audited), wall-clock timeout + canary out[0].
// ============================================================================

typedef _Float16 f16;
typedef _Float16 f16x8 __attribute__((ext_vector_type(8)));
typedef float f32x4 __attribute__((ext_vector_type(4)));
typedef unsigned long long u64;
struct U128 { u64 lo, hi; };

#define TSTEPS 2048
#define NW 32
#define RING_N 64
#define TIMEOUT_TICKS 200000000ull   // ~2 s at 100 MHz s_memrealtime

// ---- workspace layout (bytes) ----
#define BSW_OFF   0ull
#define BSW_SZ    (64ull*32768ull*2ull)
#define WHR_OFF   (BSW_OFF + BSW_SZ)
#define WHR_SZ    (64ull*4096ull*2ull)
#define BIAS_OFF  (WHR_OFF + WHR_SZ)
#define BIAS_SZ   (8192ull*4ull)
#define HBUF_OFF  (BIAS_OFF + BIAS_SZ)
#define HBUF_SZ   (32768ull*2ull)
#define RINGB_OFF (HBUF_OFF + HBUF_SZ)
#define RINGB_SZ  ((unsigned long long)RING_N*8192ull*2ull)
#define PART_OFF  (RINGB_OFF + RINGB_SZ)
#define PART_SZ   (2ull*2ull*32ull*8192ull*4ull)
#define FLAG_OFF  (PART_OFF + PART_SZ)
#define FLAG_SZ   (512ull)
#define WS_NEED   (FLAG_OFF + FLAG_SZ)

__device__ __forceinline__ float sigm(float v) {
  float e = __builtin_amdgcn_exp2f(-1.4426950408889634f * v);
  return __builtin_amdgcn_rcpf(1.0f + e);
}
__device__ __forceinline__ float tanh_(float v) {
  float a = fabsf(v);
  float e = __builtin_amdgcn_exp2f(-2.8853900817779268f * a);
  float r = (1.0f - e) * __builtin_amdgcn_rcpf(1.0f + e);
  return copysignf(r, v);
}

// ---- relaxed agent-scope atomic helpers (compile to global_* sc1) --------
__device__ __forceinline__ u64 ald64(const void* p) {
  return __hip_atomic_load((const u64*)p, __ATOMIC_RELAXED, __HIP_MEMORY_SCOPE_AGENT);
}
__device__ __forceinline__ void ast64(void* p, u64 v) {
  __hip_atomic_store((u64*)p, v, __ATOMIC_RELAXED, __HIP_MEMORY_SCOPE_AGENT);
}
__device__ __forceinline__ unsigned ald32(const void* p) {
  return __hip_atomic_load((const unsigned*)p, __ATOMIC_RELAXED, __HIP_MEMORY_SCOPE_AGENT);
}
__device__ __forceinline__ void ast32(void* p, unsigned v) {
  __hip_atomic_store((unsigned*)p, v, __ATOMIC_RELAXED, __HIP_MEMORY_SCOPE_AGENT);
}
__device__ __forceinline__ f16x8 ald_f16x8(const f16* p) {
  U128 u; u.lo = ald64(p); u.hi = ald64(p + 4);
  return __builtin_bit_cast(f16x8, u);
}
__device__ __forceinline__ f32x4 ald_f32x4(const float* p) {
  U128 u; u.lo = ald64(p); u.hi = ald64(p + 2);
  return __builtin_bit_cast(f32x4, u);
}
__device__ __forceinline__ void ast_f32x4(float* p, f32x4 v) {
  U128 u = __builtin_bit_cast(U128, v);
  ast64(p, u.lo); ast64(p + 2, u.hi);
}
__device__ __forceinline__ void vm_drain() {          // operand-free, safe
  asm volatile("s_waitcnt vmcnt(0)" ::: "memory");
}

// ---------------------------------------------------------------------------
// Setup (unchanged, round-2-proven): pack weights into per-WG MFMA-fragment
// order, sum biases, zero h buffers + flags.
// Fragment conventions (16x16x32):
//   A-frag: lane l holds A[m = l&15][k = (l>>4)*8 + i], i=0..7
//   B-frag: lane l holds B[k = (l>>4)*8 + i][n = l&15]
//   D:      lane l, reg r -> D[m = (l>>4)*4 + r][n = l&15]
// ---------------------------------------------------------------------------
__global__ void lstm_setup(
    const float* __restrict__ Wih0, const float* __restrict__ Whh0,
    const float* __restrict__ bih0, const float* __restrict__ bhh0,
    const float* __restrict__ Whr0,
    const float* __restrict__ Wih1, const float* __restrict__ Whh1,
    const float* __restrict__ bih1, const float* __restrict__ bhh1,
    const float* __restrict__ Whr1,
    f16* __restrict__ Bsw, f16* __restrict__ Whrsw, float* __restrict__ bias,
    f16* __restrict__ hbuf, unsigned* __restrict__ flags)
{
  const int blk = blockIdx.x, tid = threadIdx.x;
  if (blk < 64) {
    const int lyr = blk >> 5, w = blk & 31;
    const float* Whh = lyr ? Whh1 : Whh0;
    const float* Wih = lyr ? Wih1 : Wih0;
    f16* dst = Bsw + (size_t)blk * 32768;
    for (int e = tid; e < 32768; e += 256) {
      int i = e & 7, l = (e >> 3) & 63, ntG = (e >> 9) & 7, ks = e >> 12;
      int k  = ks * 32 + (l >> 4) * 8 + i;
      int rl = ntG * 16 + (l & 15);
      int grow = (rl >> 5) * 1024 + w * 32 + (rl & 31);
      float v = (k < 128) ? Whh[grow * 128 + k] : Wih[grow * 128 + (k - 128)];
      dst[e] = (f16)v;
    }
  } else if (blk < 128) {
    const int q = blk - 64, lyr = q >> 5, w = q & 31;
    const float* Whr = lyr ? Whr1 : Whr0;
    f16* dst = Whrsw + (size_t)q * 4096;
    for (int e = tid; e < 4096; e += 256) {
      int i = e & 7, l = (e >> 3) & 63, pnG = e >> 9;
      int p = pnG * 16 + (l & 15);
      int hg = w * 32 + (l >> 4) * 8 + i;
      dst[e] = (f16)Whr[p * 1024 + hg];
    }
  } else if (blk == 128) {
    for (int e = tid; e < 8192; e += 256) {
      int lyr = e >> 12, j = e & 4095;
      bias[e] = lyr ? (bih1[j] + bhh1[j]) : (bih0[j] + bhh0[j]);
    }
  } else {
    // zero h buffers via agent-scope stores so the main kernel's sc1 reads
    // cannot see anything stale regardless of L2 state
    for (int e = tid * 4; e < 32768; e += 1024)
      ast64(hbuf + e, 0ull);
    for (int e = tid; e < 128; e += 256)
      ast32(flags + e, 0u);
  }
}

// ---------------------------------------------------------------------------
// Main persistent kernel: 64 WGs x 256 thr (4 waves, (wy,wx) 2x2).
// blocks 0..31 = layer 0, 32..63 = layer 1 (pipelined via 64-deep ring).
// ---------------------------------------------------------------------------
__global__ __launch_bounds__(256, 1) void lstm_main(
    const float* __restrict__ x, float* __restrict__ out,
    const f16* __restrict__ Bsw, const f16* __restrict__ Whrsw,
    const float* __restrict__ bias, f16* __restrict__ hbuf,
    f16* __restrict__ ring, float* __restrict__ part,
    unsigned* __restrict__ flag1, unsigned* __restrict__ flag2)
{
  const int tid = threadIdx.x;
  const int lane = tid & 63, wv = tid >> 6;
  const int wy = wv >> 1, wx = wv & 1;
  const int l15 = lane & 15, lg = lane >> 4;
  const int w = blockIdx.x & 31, lyr = blockIdx.x >> 5;

  const unsigned long long tstart = __builtin_amdgcn_s_memrealtime();
  bool tmo = false;

  __shared__ __align__(16) f16   s_lds[64][40];
  __shared__ __align__(16) float part_lds[128][68];
  __shared__ unsigned short s_h16[4][64];
  __shared__ int s_go1, s_go2;

  if (tid == 0) { s_go1 = 0; s_go2 = 0; }
  __syncthreads();

  // ---- preload this WG's weight slice into registers (once, plain loads) --
  f16x8 bf[8][4];
  {
    const f16* bsl = Bsw + (size_t)(lyr * NW + w) * 32768;
#pragma unroll
    for (int ks = 0; ks < 8; ++ks)
#pragma unroll
      for (int ntl = 0; ntl < 4; ++ntl)
        bf[ks][ntl] = *(const f16x8*)(bsl + (((ks * 8 + (ntl * 2 + wx)) * 64 + lane) * 8));
  }
  f16x8 wf[4];
  {
    const f16* wsl = Whrsw + (size_t)(lyr * NW + w) * 4096;
#pragma unroll
    for (int pnl = 0; pnl < 4; ++pnl)
      wf[pnl] = *(const f16x8*)(wsl + (((pnl * 2 + wx) * 64 + lane) * 8));
  }
  float bias_r[4];
#pragma unroll
  for (int ntl = 0; ntl < 4; ++ntl)
    bias_r[ntl] = bias[lyr * 4096 + ntl * 1024 + w * 32 + wx * 16 + l15];

  float c[2][4] = {{0.f,0.f,0.f,0.f},{0.f,0.f,0.f,0.f}};

  unsigned* f1L  = flag1 + lyr * 32;
  unsigned* f2L  = flag2 + lyr * 32;
  unsigned* f2_0 = flag2;
  unsigned* f1_1 = flag1 + 32;
  f16* hb = hbuf + lyr * 2 * 8192;

  for (int t = 0; t < TSTEPS; ++t) {
    // ---- pre-poll: x_t (layer 0 only; plain cached loads of read-only x) --
    f16x8 xr[2][4];
    if (lyr == 0) {
#pragma unroll
      for (int mtl = 0; mtl < 2; ++mtl) {
        const int bbx = (wy * 2 + mtl) * 16 + l15;
        const float* xp = x + ((size_t)bbx * TSTEPS + t) * 128 + lg * 8;
#pragma unroll
        for (int ks2 = 0; ks2 < 4; ++ks2) {
          float4 v0 = *(const float4*)(xp + ks2 * 32);
          float4 v1 = *(const float4*)(xp + ks2 * 32 + 4);
          f16x8 hx;
          hx[0]=(f16)v0.x; hx[1]=(f16)v0.y; hx[2]=(f16)v0.z; hx[3]=(f16)v0.w;
          hx[4]=(f16)v1.x; hx[5]=(f16)v1.y; hx[6]=(f16)v1.z; hx[7]=(f16)v1.w;
          xr[mtl][ks2] = hx;
        }
      }
    }

    // ================= phase-1 wait: h_{t-1} ready (+ h1_t for layer1) ======
    if (wv == 0) {
      for (;;) {
        bool ok = true;
        if (lane < 32) {
          ok = ald32(f2L + lane) >= (unsigned)t;
          if (lyr == 1)
            ok &= ald32(f2_0 + lane) >= (unsigned)(t + 1);
        }
        if ((__builtin_amdgcn_s_memrealtime() - tstart) > TIMEOUT_TICKS) { ok = true; tmo = true; }
        if (__all(ok)) break;
        __builtin_amdgcn_s_sleep(1);
      }
      __atomic_store_n(&s_go1, t + 1, __ATOMIC_RELAXED);
    } else {
      while (__atomic_load_n(&s_go1, __ATOMIC_RELAXED) < t + 1)
        __builtin_amdgcn_s_sleep(1);
    }
    asm volatile("" ::: "memory");   // compiler barrier only (sc1 loads can't be stale)

    // ---- per-M-tile: agent-atomic A-frag loads, then MFMA (reg reuse) ----
    f32x4 acc[2][4];
    {
      const f16* hsrc = hb + ((t + 1) & 1) * 8192;        // parity (t-1)&1
      const f16* rsrc = ring + (size_t)(t & (RING_N - 1)) * 8192;
#pragma unroll
      for (int mtl = 0; mtl < 2; ++mtl) {
        const int fo = (wy * 2 + mtl) * 512 + lane * 8;
        f16x8 afm[8];
#pragma unroll
        for (int ks = 0; ks < 4; ++ks)
          afm[ks] = ald_f16x8(hsrc + fo + ks * 2048);
        if (lyr == 0) {
          afm[4] = xr[mtl][0]; afm[5] = xr[mtl][1];
          afm[6] = xr[mtl][2]; afm[7] = xr[mtl][3];
        } else {
#pragma unroll
          for (int ks2 = 0; ks2 < 4; ++ks2)
            afm[4 + ks2] = ald_f16x8(rsrc + fo + ks2 * 2048);
        }
#pragma unroll
        for (int ntl = 0; ntl < 4; ++ntl) {
          f32x4 b4 = {bias_r[ntl], bias_r[ntl], bias_r[ntl], bias_r[ntl]};
          acc[mtl][ntl] = b4;
        }
#pragma unroll
        for (int ks = 0; ks < 8; ++ks)
#pragma unroll
          for (int ntl = 0; ntl < 4; ++ntl)
            acc[mtl][ntl] = __builtin_amdgcn_mfma_f32_16x16x32_f16(
                afm[ks], bf[ks][ntl], acc[mtl][ntl], 0, 0, 0);
      }
    }

    // ---- elementwise (ntl = gate type i,f,g,o for unit (h''=wx*16+l15)) ----
#pragma unroll
    for (int mtl = 0; mtl < 2; ++mtl)
#pragma unroll
      for (int r = 0; r < 4; ++r) {
        float gi = acc[mtl][0][r];
        float gf = acc[mtl][1][r];
        float gg = acc[mtl][2][r];
        float go = acc[mtl][3][r];
        float cc = sigm(gf) * c[mtl][r] + sigm(gi) * tanh_(gg);
        c[mtl][r] = cc;
        float s = sigm(go) * tanh_(cc);
        int bb = (wy * 2 + mtl) * 16 + lg * 4 + r;
        s_lds[bb][wx * 16 + l15] = (f16)s;
      }
    __syncthreads();

    // ---- partial projection [64,32]x[32,128], K=32 in one MFMA ----
    f16x8 ap[2];
#pragma unroll
    for (int pml = 0; pml < 2; ++pml)
      ap[pml] = *(const f16x8*)(&s_lds[(wy * 2 + pml) * 16 + l15][lg * 8]);
    f32x4 pacc[2][4];
#pragma unroll
    for (int pml = 0; pml < 2; ++pml)
#pragma unroll
      for (int pnl = 0; pnl < 4; ++pnl) {
        f32x4 z = {0.f, 0.f, 0.f, 0.f};
        pacc[pml][pnl] = __builtin_amdgcn_mfma_f32_16x16x32_f16(ap[pml], wf[pnl], z, 0, 0, 0);
      }
    // transpose to p-major via LDS (row = p-local 0..127, col = batch 0..63)
#pragma unroll
    for (int pml = 0; pml < 2; ++pml)
#pragma unroll
      for (int pnl = 0; pnl < 4; ++pnl)
#pragma unroll
        for (int r = 0; r < 4; ++r)
          part_lds[(pnl * 2 + wx) * 16 + l15][(wy * 2 + pml) * 16 + lg * 4 + r] =
              pacc[pml][pnl][r];
    __syncthreads();
    // agent-atomic partial store, layout part[p][j=w][b]: fidx = p*2048+w*64+b
    {
      float* slab = part + (size_t)((lyr * 2 + (t & 1)) * 32) * 8192;
#pragma unroll
      for (int q = 0; q < 8; ++q) {
        int i4 = tid + q * 256;
        int pl = i4 >> 4, c4 = i4 & 15;
        f32x4 v = *(const f32x4*)(&part_lds[pl][c4 * 4]);
        ast_f32x4(slab + (size_t)pl * 2048 + w * 64 + c4 * 4, v);
      }
    }
    vm_drain();
    __syncthreads();                      // all waves' stores at MALL
    if (tid == 0) ast32(f1L + w, (unsigned)(t + 1));

    // ================= phase-2 wait: all partials of step t =================
    if (wv == 0) {
      for (;;) {
        bool ok = true;
        if (lane < 32) {
          ok = ald32(f1L + lane) >= (unsigned)(t + 1);
          if (lyr == 0 && t >= RING_N)   // ring-overwrite throttle
            ok &= ald32(f1_1 + lane) >= (unsigned)(t - (RING_N - 1));
        }
        if ((__builtin_amdgcn_s_memrealtime() - tstart) > TIMEOUT_TICKS) { ok = true; tmo = true; }
        if (__all(ok)) break;
        __builtin_amdgcn_s_sleep(1);
      }
      __atomic_store_n(&s_go2, t + 1, __ATOMIC_RELAXED);
    } else {
      while (__atomic_load_n(&s_go2, __ATOMIC_RELAXED) < t + 1)
        __builtin_amdgcn_s_sleep(1);
    }
    asm volatile("" ::: "memory");

    // ---- reduce 32 partials: wave = one p; lane = (jh = lane>>4, bg = lane&15)
    //      8x f32x4 agent-atomic loads + shfl_xor butterfly over jh ----
    {
      const int p = w * 4 + wv, jh = lane >> 4, bg = lane & 15;
      const float* slab = part + (size_t)((lyr * 2 + (t & 1)) * 32) * 8192;
      const float* base = slab + (size_t)p * 2048 + jh * 512 + bg * 4;
      f32x4 vs = {0.f, 0.f, 0.f, 0.f};
#pragma unroll
      for (int k2 = 0; k2 < 8; ++k2)
        vs += ald_f32x4(base + k2 * 64);
#pragma unroll
      for (int e = 0; e < 4; ++e) {
        float s = vs[e];
        s += __shfl_xor(s, 16);
        s += __shfl_xor(s, 32);
        vs[e] = s;
      }
      if (jh == 0) {
        if (lyr == 1 && t >= TSTEPS - 64) {
#pragma unroll
          for (int e = 0; e < 4; ++e)
            out[(size_t)(bg * 4 + e) * 8192 + (t - (TSTEPS - 64)) * 128 + p] = vs[e];
        }
#pragma unroll
        for (int e = 0; e < 4; ++e) {
          f16 hv = (f16)vs[e];
          s_h16[wv][bg * 4 + e] = __builtin_bit_cast(unsigned short, hv);
        }
      }
    }
    __syncthreads();
    // paired u32 agent-atomic h-store (threads 0..127), A-frag layout
    if (tid < 128) {
      const int half = tid >> 6, b2 = tid & 63;
      const int pe = w * 4 + half * 2;                    // even p
      unsigned pk = (unsigned)s_h16[half * 2][b2] |
                    ((unsigned)s_h16[half * 2 + 1][b2] << 16);
      const int cidx = (((pe >> 5) * 4 + (b2 >> 4)) * 64 +
                        ((pe >> 3) & 3) * 16 + (b2 & 15)) * 8 + (pe & 7);
      ast32(hb + (t & 1) * 8192 + cidx, pk);
      if (lyr == 0)
        ast32(ring + (size_t)(t & (RING_N - 1)) * 8192 + cidx, pk);
    }
    vm_drain();
    __syncthreads();
    if (tid == 0) ast32(f2L + w, (unsigned)(t + 1));
  }

  // timeout canary: protocol livelock shows as absmax ~12345, not NaN/zeros
  if (tmo && tid == 0) out[0] = 12345.0f;
}

extern "C" void kernel_launch(void* const* d_in, const int* in_sizes, int n_in,
                              void* d_out, int out_size, void* d_ws, size_t ws_size,
                              hipStream_t stream)
{
  const float* x    = (const float*)d_in[0];
  const float* Wih0 = (const float*)d_in[1];
  const float* Whh0 = (const float*)d_in[2];
  const float* bih0 = (const float*)d_in[3];
  const float* bhh0 = (const float*)d_in[4];
  const float* Whr0 = (const float*)d_in[5];
  const float* Wih1 = (const float*)d_in[6];
  const float* Whh1 = (const float*)d_in[7];
  const float* bih1 = (const float*)d_in[8];
  const float* bhh1 = (const float*)d_in[9];
  const float* Whr1 = (const float*)d_in[10];

  if (ws_size < WS_NEED) return;

  char* ws = (char*)d_ws;
  f16*      Bsw   = (f16*)(ws + BSW_OFF);
  f16*      Whrsw = (f16*)(ws + WHR_OFF);
  float*    bias  = (float*)(ws + BIAS_OFF);
  f16*      hbuf  = (f16*)(ws + HBUF_OFF);
  f16*      ring  = (f16*)(ws + RINGB_OFF);
  float*    part  = (float*)(ws + PART_OFF);
  unsigned* flags = (unsigned*)(ws + FLAG_OFF);
  unsigned* flag1 = flags;        // [2][32]
  unsigned* flag2 = flags + 64;   // [2][32]

  lstm_setup<<<130, 256, 0, stream>>>(Wih0, Whh0, bih0, bhh0, Whr0,
                                      Wih1, Whh1, bih1, bhh1, Whr1,
                                      Bsw, Whrsw, bias, hbuf, flags);
  lstm_main<<<64, 256, 0, stream>>>(x, (float*)d_out, Bsw, Whrsw, bias,
                                    hbuf, ring, part, flag1, flag2);
}